// Round 8
// baseline (337.455 us; speedup 1.0000x reference)
//
#include <hip/hip_runtime.h>
#include <hip/hip_bf16.h>

#define D 32

typedef const float* fp;
typedef unsigned short u16;
typedef unsigned int u32;

using short8 = __attribute__((ext_vector_type(8))) short;
using f32x4  = __attribute__((ext_vector_type(4))) float;

__device__ __forceinline__ float b2f(u32 lo16) { return __uint_as_float(lo16 << 16); }
__device__ __forceinline__ u16 f2b(float f) {
    u32 x = __float_as_uint(f);
    return (u16)((x + 0x7fffu + ((x >> 16) & 1u)) >> 16);   // RNE
}

// h (f32+bf16), u, v from x; P (precomposed 2x32 edge weights) computed per-block in LDS;
// also zeroes a/cnt/cursor for this call
__global__ void k_hev(fp x, fp W_emb, fp b_emb, fp Wth, fp bth, fp Wph, fp bph,
                      float* __restrict__ h, u16* __restrict__ hbf,
                      float* __restrict__ u, float* __restrict__ v,
                      float* __restrict__ a, int* __restrict__ cnt,
                      int* __restrict__ cursor, int Npad, int N) {
    __shared__ float sP[192];
    int tid = threadIdx.x;
    if (tid < 32) {
        int o = tid;
        float au0 = 0.f, au1 = 0.f, cu = 0.f, av0 = 0.f, av1 = 0.f, cv = 0.f;
        for (int i = 0; i < D; ++i) {
            float wt = Wth[i * D + o];
            float wd = Wph[i * D + o] - wt;
            au0 += W_emb[i] * wt;
            au1 += W_emb[D + i] * wt;
            cu  += b_emb[i] * wt;
            av0 += W_emb[i] * wd;
            av1 += W_emb[D + i] * wd;
            cv  += b_emb[i] * wd;
        }
        sP[o]       = au0;
        sP[32 + o]  = au1;
        sP[64 + o]  = cu + bth[o] + bph[o];
        sP[96 + o]  = av0;
        sP[128 + o] = av1;
        sP[160 + o] = cv;
    }
    __syncthreads();
    int t = blockIdx.x * 256 + tid;
    if (t >= N * D) return;
    a[t] = 0.f;
    if (t < Npad) cnt[t] = 0;
    if (t < N) cursor[t] = 0;
    int n = t >> 5, o = t & 31;
    float x0 = x[2 * n], x1 = x[2 * n + 1];
    float hv = x0 * W_emb[o] + x1 * W_emb[D + o] + b_emb[o];
    h[t] = hv;
    hbf[t] = f2b(hv);
    u[t] = x0 * sP[o] + x1 * sP[32 + o] + sP[64 + o];
    v[t] = x0 * sP[96 + o] + x1 * sP[128 + o] + sP[160 + o];
}

// W2 -> MFMA-B-fragment layout: W2f[T*512 + l*8 + j] = bf16(W2e[i=(l>>4)*8+j][ko=T*16+(l&15)])
__global__ void k_w2frag(fp W2, u16* __restrict__ W2f) {
    int idx = blockIdx.x * 256 + threadIdx.x;   // 65536 total
    int T = idx >> 9, r = idx & 511, l = r >> 3, j = r & 7;
    int ko = T * 16 + (l & 15);
    int i = (l >> 4) * 8 + j;
    W2f[idx] = f2b(W2[(size_t)(ko >> 5) * 1024 + i * 32 + (ko & 31)]);
}

__global__ void k_count(const int* __restrict__ src, int* __restrict__ cnt, int E) {
    int e = blockIdx.x * 256 + threadIdx.x;
    if (e < E) atomicAdd(&cnt[src[e]], 1);
}

__global__ void k_scan(const int* __restrict__ cnt, int* __restrict__ roff, int N) {
    __shared__ int part[1024];
    int t = threadIdx.x;
    int per = (N + 1023) / 1024;
    int begin = t * per, end = min(begin + per, N);
    int s = 0;
    for (int i = begin; i < end; ++i) s += cnt[i];
    part[t] = s;
    __syncthreads();
    for (int off = 1; off < 1024; off <<= 1) {
        int v = (t >= off) ? part[t - off] : 0;
        __syncthreads();
        part[t] += v;
        __syncthreads();
    }
    int pre = (t == 0) ? 0 : part[t - 1];
    for (int i = begin; i < end; ++i) { roff[i] = pre; pre += cnt[i]; }
    if (t == 0) roff[N] = part[1023];
}

__global__ void k_scatter(const int* __restrict__ src, const int* __restrict__ dst,
                          const int* __restrict__ roff, int* __restrict__ cursor,
                          int* __restrict__ ssrc, int* __restrict__ sdst, int E) {
    int e = blockIdx.x * 256 + threadIdx.x;
    if (e >= E) return;
    int s = src[e];
    int p = roff[s] + atomicAdd(&cursor[s], 1);
    ssrc[p] = s;
    sdst[p] = dst[e];
}

// cooperative: 8 edges/block; lane o owns g[k=2o,2o+1]; he staged in LDS
__global__ __launch_bounds__(256)
void k_edge2(const float* __restrict__ u, const float* __restrict__ v,
             const int* __restrict__ ssrc, const int* __restrict__ sdst,
             fp W1, fp b1, u16* __restrict__ g, int E) {
    __shared__ float sW1[D * 64];
    __shared__ float sb1[64];
    __shared__ float she[8][D];
    for (int i = threadIdx.x; i < D * 64; i += 256) sW1[i] = W1[i];
    if (threadIdx.x < 64) sb1[threadIdx.x] = b1[threadIdx.x];
    __syncthreads();
    int sub = threadIdx.x >> 5, o = threadIdx.x & 31;
    const float2* w2p = (const float2*)sW1;
    for (int e0 = blockIdx.x * 8; e0 < E; e0 += gridDim.x * 8) {
        int e = e0 + sub;
        if (e < E) {
            int s = ssrc[e], d2 = sdst[e];
            she[sub][o] = fmaxf(u[(size_t)d2 * D + o] + v[(size_t)s * D + o], 0.f);
        }
        __syncthreads();
        if (e < E) {
            float a0 = sb1[2 * o], a1 = sb1[2 * o + 1];
            #pragma unroll
            for (int i = 0; i < D; ++i) {
                float hv = she[sub][i];
                float2 w = w2p[i * 32 + o];
                a0 += hv * w.x;
                a1 += hv * w.y;
            }
            ((u32*)g)[(size_t)e * 32 + o] =
                (u32)f2b(fmaxf(a0, 0.f)) | ((u32)f2b(fmaxf(a1, 0.f)) << 16);
        }
        __syncthreads();
    }
}

// Fused per-step kernel: block owns 8 src nodes.
// Phase1: M rows (8x2048) by MFMA into LDS, column-major stride-66 (bank-conflict-free).
// Phase2: per half-wave sub s0+sub: inline B, then per out-edge apply M row + atomicAdd.
#define CSTR 66          // column stride in u16 (64 k-values + 2 pad)
#define LROW 2116        // per-src LDS row: 32 cols * 66 + 4 (u16 units, keeps 4B align)
__global__ __launch_bounds__(256, 4)
void k_msgM(const u16* __restrict__ hbf, const u16* __restrict__ W2f,
            const float* __restrict__ h, fp b2,
            const u16* __restrict__ g, const int* __restrict__ roff,
            const int* __restrict__ sdst, float* __restrict__ a, int N) {
    __shared__ u16 sM[8 * LROW];
    __shared__ float sgf[8][64];
    int s0 = blockIdx.x * 8;
    if (s0 >= N) return;
    int sHi = min(s0 + 8, N);
    if (roff[s0] >= roff[sHi]) return;      // no out-edges in this block

    // ---- phase 1: MFMA ----
    int w = threadIdx.x >> 6, l = threadIdx.x & 63;
    int r15 = l & 15;
    int arow = (r15 < 8 && s0 + r15 < N) ? (s0 + r15) : s0;
    short8 afrag = *(const short8*)(hbf + (size_t)arow * 32 + (l >> 4) * 8);
    int rbase = (l >> 4) * 4;               // C-row base: {0,4,8,12}
    int col = l & 15;                       // C-col = ko within tile
    #pragma unroll 4
    for (int tt = 0; tt < 32; ++tt) {
        int T = w * 32 + tt;                // tile: ko = T*16 .. T*16+15
        short8 bfrag = *(const short8*)(W2f + (size_t)T * 512 + l * 8);
        f32x4 acc{0.f, 0.f, 0.f, 0.f};
        acc = __builtin_amdgcn_mfma_f32_16x16x32_bf16(afrag, bfrag, acc, 0, 0, 0);
        if (rbase < 8) {                    // rows 0..7 are the real srcs
            int k = T >> 1;                 // ko = k*32 + o ; o = (T&1)*16 + col
            int o_val = ((T & 1) << 4) + col;
            #pragma unroll
            for (int r = 0; r < 4; ++r)
                sM[(rbase + r) * LROW + o_val * CSTR + k] = f2b(acc[r]);
        }
    }
    __syncthreads();

    // ---- phase 2: edges, no barriers (in-wave LDS ordering) ----
    int sub = threadIdx.x >> 5, o = threadIdx.x & 31;
    int s = s0 + sub;
    if (s >= N) return;
    int beg = roff[s], end = roff[s + 1];
    if (beg >= end) return;
    // B[s][o] inline (L2-hot reads)
    float Bso = 0.f;
    const float* hrow = h + (size_t)s * 32;
    #pragma unroll 8
    for (int i = 0; i < 32; ++i) Bso += hrow[i] * b2[i * 32 + o];

    const u32* sMrow = (const u32*)(sM + sub * LROW + o * CSTR);  // 33*o dwords, 4B-aligned
    for (int p = beg; p < end; ++p) {
        u32 pk = ((const u32*)g)[(size_t)p * 32 + o];
        sgf[sub][2 * o]     = b2f(pk & 0xffff);
        sgf[sub][2 * o + 1] = b2f(pk >> 16);
        float acc = Bso;
        #pragma unroll
        for (int q = 0; q < 32; ++q) {
            u32 m2 = sMrow[q];                       // M[s][2q*32+o] | M[s][(2q+1)*32+o]
            acc += sgf[sub][2 * q]     * b2f(m2 & 0xffff)
                 + sgf[sub][2 * q + 1] * b2f(m2 >> 16);
        }
        atomicAdd(&a[(size_t)sdst[p] * D + o], acc);
    }
}

// torch GRUCell, weights in LDS; zeroes a in place; writes f32 + bf16 h
__global__ __launch_bounds__(256)
void k_gru(float* __restrict__ a, const float* __restrict__ h,
           fp W_ih, fp b_ih, fp W_hh, fp b_hh,
           float* __restrict__ hout, u16* __restrict__ hbf, int N) {
    __shared__ float sWi[D * 96], sWh[D * 96], sbi[96], sbh[96];
    __shared__ float sa[8][D], sh[8][D];
    for (int i = threadIdx.x; i < D * 96; i += 256) { sWi[i] = W_ih[i]; sWh[i] = W_hh[i]; }
    if (threadIdx.x < 96) { sbi[threadIdx.x] = b_ih[threadIdx.x]; sbh[threadIdx.x] = b_hh[threadIdx.x]; }
    int n0 = blockIdx.x * 8;
    for (int i = threadIdx.x; i < 8 * D; i += 256) {
        int n = n0 + (i >> 5);
        if (n < N) {
            size_t idx = (size_t)n * D + (i & 31);
            sa[i >> 5][i & 31] = a[idx];
            sh[i >> 5][i & 31] = h[idx];
            a[idx] = 0.f;
        }
    }
    __syncthreads();
    int sub = threadIdx.x >> 5, o = threadIdx.x & 31;
    int n = n0 + sub;
    if (n >= N) return;
    float ir = sbi[o], iz = sbi[D + o], in_ = sbi[2 * D + o];
    float hr = sbh[o], hz = sbh[D + o], hn = sbh[2 * D + o];
    #pragma unroll
    for (int i = 0; i < D; ++i) {
        float av = sa[sub][i], hv = sh[sub][i];
        ir += av * sWi[i * 96 + o];
        iz += av * sWi[i * 96 + D + o];
        in_ += av * sWi[i * 96 + 2 * D + o];
        hr += hv * sWh[i * 96 + o];
        hz += hv * sWh[i * 96 + D + o];
        hn += hv * sWh[i * 96 + 2 * D + o];
    }
    float r = 1.f / (1.f + __expf(-(ir + hr)));
    float z = 1.f / (1.f + __expf(-(iz + hz)));
    float nn = tanhf(in_ + r * hn);
    float hv2 = (1.f - z) * nn + z * sh[sub][o];
    size_t idx = (size_t)n * D + o;
    hout[idx] = hv2;
    hbf[idx] = f2b(hv2);
}

extern "C" void kernel_launch(void* const* d_in, const int* in_sizes, int n_in,
                              void* d_out, int out_size, void* d_ws, size_t ws_size,
                              hipStream_t stream) {
    fp x      = (fp)d_in[0];
    const int* src = (const int*)d_in[1];
    const int* dst = (const int*)d_in[2];
    fp W_emb  = (fp)d_in[3];
    fp b_emb  = (fp)d_in[4];
    fp W_th   = (fp)d_in[5];
    fp b_th   = (fp)d_in[6];
    fp W_ph   = (fp)d_in[7];
    fp b_ph   = (fp)d_in[8];
    fp W1     = (fp)d_in[9];
    fp b1     = (fp)d_in[10];
    fp W2     = (fp)d_in[11];
    fp b2     = (fp)d_in[12];
    fp W_ih   = (fp)d_in[13];
    fp b_ih   = (fp)d_in[14];
    fp W_hh   = (fp)d_in[15];
    fp b_hh   = (fp)d_in[16];

    const int N = in_sizes[0] / 2;
    const int E = in_sizes[1];
    const int Npad = N + 4 - (N % 4);

    float* a      = (float*)d_ws;                       // N*D f32
    int*   cnt    = (int*)(a + (size_t)N * D);          // Npad
    int*   cursor = cnt + Npad;                         // N
    int*   roff   = cursor + N;                         // Npad (N+1 used)
    int*   ssrc   = roff + Npad;                        // E
    int*   sdst   = ssrc + E;                           // E
    float* hA     = (float*)(sdst + E);                 // N*D
    float* hB     = hA + (size_t)N * D;                 // N*D
    u16*   g      = (u16*)(hB + (size_t)N * D);         // E*64 bf16
    u16*   hbf    = g + (size_t)E * 64;                 // N*D bf16
    u16*   W2f    = hbf + (size_t)N * D;                // 65536 bf16
    float* u      = (float*)(W2f + 65536);              // N*D
    float* v      = u + (size_t)N * D;                  // N*D

    int ndBlocks = (N * D + 255) / 256;
    int eBlocks  = (E + 255) / 256;

    k_hev<<<ndBlocks, 256, 0, stream>>>(x, W_emb, b_emb, W_th, b_th, W_ph, b_ph,
                                        hA, hbf, u, v, a, cnt, cursor, Npad, N);
    k_w2frag<<<256, 256, 0, stream>>>(W2, W2f);
    k_count<<<eBlocks, 256, 0, stream>>>(src, cnt, E);
    k_scan<<<1, 1024, 0, stream>>>(cnt, roff, N);
    k_scatter<<<eBlocks, 256, 0, stream>>>(src, dst, roff, cursor, ssrc, sdst, E);
    k_edge2<<<2048, 256, 0, stream>>>(u, v, ssrc, sdst, W1, b1, g, E);

    int fBlocks = (N + 7) / 8;
    float* hc = hA;
    float* hn_ = hB;
    for (int step = 0; step < 3; ++step) {
        k_msgM<<<fBlocks, 256, 0, stream>>>(hbf, W2f, hc, b2, g, roff, sdst, a, N);
        float* dstbuf = (step == 2) ? (float*)d_out : hn_;
        k_gru<<<fBlocks, 256, 0, stream>>>(a, hc, W_ih, b_ih, W_hh, b_hh, dstbuf, hbf, N);
        float* t = hc; hc = hn_; hn_ = t;
    }
}

// Round 9
// 294.946 us; speedup vs baseline: 1.1441x; 1.1441x over previous
//
#include <hip/hip_runtime.h>
#include <hip/hip_bf16.h>

#define D 32

typedef const float* fp;
typedef unsigned short u16;
typedef unsigned int u32;

using short8 = __attribute__((ext_vector_type(8))) short;
using f32x4  = __attribute__((ext_vector_type(4))) float;

__device__ __forceinline__ float b2f(u32 lo16) { return __uint_as_float(lo16 << 16); }
__device__ __forceinline__ u16 f2b(float f) {
    u32 x = __float_as_uint(f);
    return (u16)((x + 0x7fffu + ((x >> 16) & 1u)) >> 16);   // RNE
}

// wave-local LDS fence: all this wave's LDS ops retired; block compiler reordering
__device__ __forceinline__ void wave_lds_fence() {
    asm volatile("s_waitcnt lgkmcnt(0)" ::: "memory");
    __builtin_amdgcn_sched_barrier(0);
}

// h (f32+bf16), u, v from x; P precomposed in LDS; zeroes a/cnt/cursor
__global__ void k_hev(fp x, fp W_emb, fp b_emb, fp Wth, fp bth, fp Wph, fp bph,
                      float* __restrict__ h, u16* __restrict__ hbf,
                      float* __restrict__ u, float* __restrict__ v,
                      float* __restrict__ a, int* __restrict__ cnt,
                      int* __restrict__ cursor, int Npad, int N) {
    __shared__ float sP[192];
    int tid = threadIdx.x;
    if (tid < 32) {
        int o = tid;
        float au0 = 0.f, au1 = 0.f, cu = 0.f, av0 = 0.f, av1 = 0.f, cv = 0.f;
        for (int i = 0; i < D; ++i) {
            float wt = Wth[i * D + o];
            float wd = Wph[i * D + o] - wt;
            au0 += W_emb[i] * wt;
            au1 += W_emb[D + i] * wt;
            cu  += b_emb[i] * wt;
            av0 += W_emb[i] * wd;
            av1 += W_emb[D + i] * wd;
            cv  += b_emb[i] * wd;
        }
        sP[o]       = au0;
        sP[32 + o]  = au1;
        sP[64 + o]  = cu + bth[o] + bph[o];
        sP[96 + o]  = av0;
        sP[128 + o] = av1;
        sP[160 + o] = cv;
    }
    __syncthreads();
    int t = blockIdx.x * 256 + tid;
    if (t >= N * D) return;
    a[t] = 0.f;
    if (t < Npad) cnt[t] = 0;
    if (t < N) cursor[t] = 0;
    int n = t >> 5, o = t & 31;
    float x0 = x[2 * n], x1 = x[2 * n + 1];
    float hv = x0 * W_emb[o] + x1 * W_emb[D + o] + b_emb[o];
    h[t] = hv;
    hbf[t] = f2b(hv);
    u[t] = x0 * sP[o] + x1 * sP[32 + o] + sP[64 + o];
    v[t] = x0 * sP[96 + o] + x1 * sP[128 + o] + sP[160 + o];
}

// W2 -> MFMA-B-fragment layout
__global__ void k_w2frag(fp W2, u16* __restrict__ W2f) {
    int idx = blockIdx.x * 256 + threadIdx.x;   // 65536 total
    int T = idx >> 9, r = idx & 511, l = r >> 3, j = r & 7;
    int ko = T * 16 + (l & 15);
    int i = (l >> 4) * 8 + j;
    W2f[idx] = f2b(W2[(size_t)(ko >> 5) * 1024 + i * 32 + (ko & 31)]);
}

__global__ void k_count(const int* __restrict__ src, int* __restrict__ cnt, int E) {
    int e = blockIdx.x * 256 + threadIdx.x;
    if (e < E) atomicAdd(&cnt[src[e]], 1);
}

__global__ void k_scan(const int* __restrict__ cnt, int* __restrict__ roff, int N) {
    __shared__ int part[1024];
    int t = threadIdx.x;
    int per = (N + 1023) / 1024;
    int begin = t * per, end = min(begin + per, N);
    int s = 0;
    for (int i = begin; i < end; ++i) s += cnt[i];
    part[t] = s;
    __syncthreads();
    for (int off = 1; off < 1024; off <<= 1) {
        int v = (t >= off) ? part[t - off] : 0;
        __syncthreads();
        part[t] += v;
        __syncthreads();
    }
    int pre = (t == 0) ? 0 : part[t - 1];
    for (int i = begin; i < end; ++i) { roff[i] = pre; pre += cnt[i]; }
    if (t == 0) roff[N] = part[1023];
}

__global__ void k_scatter(const int* __restrict__ src, const int* __restrict__ dst,
                          const int* __restrict__ roff, int* __restrict__ cursor,
                          int* __restrict__ ssrc, int* __restrict__ sdst, int E) {
    int e = blockIdx.x * 256 + threadIdx.x;
    if (e >= E) return;
    int s = src[e];
    int p = roff[s] + atomicAdd(&cursor[s], 1);
    ssrc[p] = s;
    sdst[p] = dst[e];
}

// cooperative: 8 edges/block; lane o owns g[k=2o,2o+1]; he staged in LDS
__global__ __launch_bounds__(256)
void k_edge2(const float* __restrict__ u, const float* __restrict__ v,
             const int* __restrict__ ssrc, const int* __restrict__ sdst,
             fp W1, fp b1, u16* __restrict__ g, int E) {
    __shared__ float sW1[D * 64];
    __shared__ float sb1[64];
    __shared__ float she[8][D];
    for (int i = threadIdx.x; i < D * 64; i += 256) sW1[i] = W1[i];
    if (threadIdx.x < 64) sb1[threadIdx.x] = b1[threadIdx.x];
    __syncthreads();
    int sub = threadIdx.x >> 5, o = threadIdx.x & 31;
    const float2* w2p = (const float2*)sW1;
    for (int e0 = blockIdx.x * 8; e0 < E; e0 += gridDim.x * 8) {
        int e = e0 + sub;
        if (e < E) {
            int s = ssrc[e], d2 = sdst[e];
            she[sub][o] = fmaxf(u[(size_t)d2 * D + o] + v[(size_t)s * D + o], 0.f);
        }
        __syncthreads();
        if (e < E) {
            float a0 = sb1[2 * o], a1 = sb1[2 * o + 1];
            #pragma unroll
            for (int i = 0; i < D; ++i) {
                float hv = she[sub][i];
                float2 w = w2p[i * 32 + o];
                a0 += hv * w.x;
                a1 += hv * w.y;
            }
            ((u32*)g)[(size_t)e * 32 + o] =
                (u32)f2b(fmaxf(a0, 0.f)) | ((u32)f2b(fmaxf(a1, 0.f)) << 16);
        }
        __syncthreads();
    }
}

// MFMA M-GEMM; output layout Mt[s][q][o] (u32 = bf16 pair k=2q | k=2q+1),
// block = 16 n x 256 ko (= 8 k = 4 q), epilogue stores block-contiguous 512B per row.
__global__ __launch_bounds__(256)
void k_Mm(const u16* __restrict__ hbf, const u16* __restrict__ W2f,
          u32* __restrict__ Mt, int N) {
    __shared__ u16 sM[16][264];
    int n0 = (blockIdx.x >> 3) * 16;
    if (n0 >= N) return;
    int koBase = (blockIdx.x & 7) * 256;
    int qb = (blockIdx.x & 7) * 4;
    int w = threadIdx.x >> 6, l = threadIdx.x & 63;
    int arow = n0 + (l & 15);
    if (arow >= N) arow = N - 1;
    short8 afrag = *(const short8*)(hbf + (size_t)arow * 32 + (l >> 4) * 8);
    int T0 = (koBase >> 4) + w * 4;
    const u16* bp = W2f + (size_t)T0 * 512 + l * 8;
    short8 b0 = *(const short8*)(bp);
    short8 b1 = *(const short8*)(bp + 512);
    short8 b2v = *(const short8*)(bp + 1024);
    short8 b3 = *(const short8*)(bp + 1536);
    f32x4 acc0{0.f,0.f,0.f,0.f}, acc1{0.f,0.f,0.f,0.f}, acc2{0.f,0.f,0.f,0.f}, acc3{0.f,0.f,0.f,0.f};
    acc0 = __builtin_amdgcn_mfma_f32_16x16x32_bf16(afrag, b0, acc0, 0, 0, 0);
    acc1 = __builtin_amdgcn_mfma_f32_16x16x32_bf16(afrag, b1, acc1, 0, 0, 0);
    acc2 = __builtin_amdgcn_mfma_f32_16x16x32_bf16(afrag, b2v, acc2, 0, 0, 0);
    acc3 = __builtin_amdgcn_mfma_f32_16x16x32_bf16(afrag, b3, acc3, 0, 0, 0);
    int rbase = (l >> 4) * 4, col = l & 15;
    #pragma unroll
    for (int r = 0; r < 4; ++r) {
        sM[rbase + r][w * 64 +  0 + col] = f2b(acc0[r]);
        sM[rbase + r][w * 64 + 16 + col] = f2b(acc1[r]);
        sM[rbase + r][w * 64 + 32 + col] = f2b(acc2[r]);
        sM[rbase + r][w * 64 + 48 + col] = f2b(acc3[r]);
    }
    __syncthreads();
    // epilogue: pack pairs (k=2q,2q+1) -> Mt[n][q][o], contiguous 128-u32 slice per row
    int i = threadIdx.x >> 4;
    int base = (threadIdx.x & 15) * 8;
    if (n0 + i >= N) return;
    u32 out[8];
    #pragma unroll
    for (int z = 0; z < 8; ++z) {
        int idx = base + z;            // 0..127 within the 4q x 32o slice
        int qq = idx >> 5;             // local q 0..3 (local k = 2qq, 2qq+1)
        int o  = idx & 31;
        u32 lo = sM[i][(2 * qq) * 32 + o];
        u32 hi = sM[i][(2 * qq + 1) * 32 + o];
        out[z] = lo | (hi << 16);
    }
    u32* dst = Mt + (size_t)(n0 + i) * 1024 + qb * 32 + base;
    *(uint4*)dst       = make_uint4(out[0], out[1], out[2], out[3]);
    *(uint4*)(dst + 4) = make_uint4(out[4], out[5], out[6], out[7]);
}

// B[n][o] = sum_i h[n][i] * b2[i*32+o]
__global__ __launch_bounds__(256)
void k_B(const float* __restrict__ h, fp b2, float* __restrict__ B, int N) {
    __shared__ float sb2[1024];
    for (int i = threadIdx.x; i < 1024; i += 256) sb2[i] = b2[i];
    __syncthreads();
    int t = blockIdx.x * 256 + threadIdx.x;
    if (t >= N * D) return;
    int n = t >> 5, o = t & 31;
    const float4* hv = (const float4*)(h + (size_t)n * D);
    float acc = 0.f;
    #pragma unroll
    for (int i4 = 0; i4 < 8; ++i4) {
        float4 v = hv[i4];
        acc += v.x * sb2[(4 * i4) * 32 + o] + v.y * sb2[(4 * i4 + 1) * 32 + o]
             + v.z * sb2[(4 * i4 + 2) * 32 + o] + v.w * sb2[(4 * i4 + 3) * 32 + o];
    }
    B[t] = acc;
}

// wave-per-src message kernel: sM column-major (stride 33 u32, conflict-free reads),
// 2 edges in flight per wave, software-pipelined g prefetch, no block barriers.
__global__ __launch_bounds__(256)
void k_msg2(const u32* __restrict__ Mt, const float* __restrict__ B,
            const u16* __restrict__ g, const int* __restrict__ roff,
            const int* __restrict__ sdst, float* __restrict__ a, int N) {
    __shared__ u32 sMb[4][33 * 32];     // per-wave M: sMb[wv][o*33 + q]
    __shared__ float sgf[4][2][64];     // per-wave, per-sub g row (f32)
    int wv = threadIdx.x >> 6, l = threadIdx.x & 63;
    int s = blockIdx.x * 4 + wv;
    if (s >= N) return;
    int beg = roff[s], end = roff[s + 1];
    if (beg >= end) return;

    // load Mt row (4KB, coalesced): lane l covers q=l>>1, o = 16*(l&1)+m
    {
        const uint4* srcp = (const uint4*)(Mt + (size_t)s * 1024 + l * 16);
        uint4 v0 = srcp[0], v1 = srcp[1], v2 = srcp[2], v3 = srcp[3];
        u32 vals[16] = {v0.x,v0.y,v0.z,v0.w, v1.x,v1.y,v1.z,v1.w,
                        v2.x,v2.y,v2.z,v2.w, v3.x,v3.y,v3.z,v3.w};
        int q = l >> 1, ob = (l & 1) * 16;
        #pragma unroll
        for (int m = 0; m < 16; ++m)
            sMb[wv][(ob + m) * 33 + q] = vals[m];
    }
    int sub = l >> 5, o = l & 31;
    float Bso = B[(size_t)s * D + o];
    const u32* mcol = &sMb[wv][o * 33];
    const u32* g32 = (const u32*)g;

    int p = beg + sub;
    u32 pk = (p < end) ? g32[(size_t)p * 32 + o] : 0;
    for (; p < end; p += 2) {
        u32 nk = (p + 2 < end) ? g32[(size_t)(p + 2) * 32 + o] : 0;
        int dnode = sdst[p];
        sgf[wv][sub][2 * o]     = b2f(pk & 0xffff);
        sgf[wv][sub][2 * o + 1] = b2f(pk >> 16);
        wave_lds_fence();                       // sgf (and sM on first iter) visible
        float acc = Bso;
        #pragma unroll
        for (int q = 0; q < 32; ++q) {
            u32 m2 = mcol[q];
            float flo = __uint_as_float(m2 << 16);
            float fhi = __uint_as_float(m2 & 0xffff0000u);
            acc += sgf[wv][sub][2 * q] * flo + sgf[wv][sub][2 * q + 1] * fhi;
        }
        atomicAdd(&a[(size_t)dnode * D + o], acc);
        pk = nk;
    }
}

// torch GRUCell, weights in LDS; zeroes a in place; writes f32 + bf16 h
__global__ __launch_bounds__(256)
void k_gru(float* __restrict__ a, const float* __restrict__ h,
           fp W_ih, fp b_ih, fp W_hh, fp b_hh,
           float* __restrict__ hout, u16* __restrict__ hbf, int N) {
    __shared__ float sWi[D * 96], sWh[D * 96], sbi[96], sbh[96];
    __shared__ float sa[8][D], sh[8][D];
    for (int i = threadIdx.x; i < D * 96; i += 256) { sWi[i] = W_ih[i]; sWh[i] = W_hh[i]; }
    if (threadIdx.x < 96) { sbi[threadIdx.x] = b_ih[threadIdx.x]; sbh[threadIdx.x] = b_hh[threadIdx.x]; }
    int n0 = blockIdx.x * 8;
    for (int i = threadIdx.x; i < 8 * D; i += 256) {
        int n = n0 + (i >> 5);
        if (n < N) {
            size_t idx = (size_t)n * D + (i & 31);
            sa[i >> 5][i & 31] = a[idx];
            sh[i >> 5][i & 31] = h[idx];
            a[idx] = 0.f;
        }
    }
    __syncthreads();
    int sub = threadIdx.x >> 5, o = threadIdx.x & 31;
    int n = n0 + sub;
    if (n >= N) return;
    float ir = sbi[o], iz = sbi[D + o], in_ = sbi[2 * D + o];
    float hr = sbh[o], hz = sbh[D + o], hn = sbh[2 * D + o];
    #pragma unroll
    for (int i = 0; i < D; ++i) {
        float av = sa[sub][i], hv = sh[sub][i];
        ir += av * sWi[i * 96 + o];
        iz += av * sWi[i * 96 + D + o];
        in_ += av * sWi[i * 96 + 2 * D + o];
        hr += hv * sWh[i * 96 + o];
        hz += hv * sWh[i * 96 + D + o];
        hn += hv * sWh[i * 96 + 2 * D + o];
    }
    float r = 1.f / (1.f + __expf(-(ir + hr)));
    float z = 1.f / (1.f + __expf(-(iz + hz)));
    float nn = tanhf(in_ + r * hn);
    float hv2 = (1.f - z) * nn + z * sh[sub][o];
    size_t idx = (size_t)n * D + o;
    hout[idx] = hv2;
    hbf[idx] = f2b(hv2);
}

extern "C" void kernel_launch(void* const* d_in, const int* in_sizes, int n_in,
                              void* d_out, int out_size, void* d_ws, size_t ws_size,
                              hipStream_t stream) {
    fp x      = (fp)d_in[0];
    const int* src = (const int*)d_in[1];
    const int* dst = (const int*)d_in[2];
    fp W_emb  = (fp)d_in[3];
    fp b_emb  = (fp)d_in[4];
    fp W_th   = (fp)d_in[5];
    fp b_th   = (fp)d_in[6];
    fp W_ph   = (fp)d_in[7];
    fp b_ph   = (fp)d_in[8];
    fp W1     = (fp)d_in[9];
    fp b1     = (fp)d_in[10];
    fp W2     = (fp)d_in[11];
    fp b2     = (fp)d_in[12];
    fp W_ih   = (fp)d_in[13];
    fp b_ih   = (fp)d_in[14];
    fp W_hh   = (fp)d_in[15];
    fp b_hh   = (fp)d_in[16];

    const int N = in_sizes[0] / 2;
    const int E = in_sizes[1];
    const int Npad = N + 4 - (N % 4);

    float* a      = (float*)d_ws;                       // N*D f32
    int*   cnt    = (int*)(a + (size_t)N * D);          // Npad
    int*   cursor = cnt + Npad;                         // N
    int*   roff   = cursor + N;                         // Npad (N+1 used)
    int*   ssrc   = roff + Npad;                        // E
    int*   sdst   = ssrc + E;                           // E
    float* hA     = (float*)(sdst + E);                 // N*D
    float* hB     = hA + (size_t)N * D;                 // N*D
    u16*   g      = (u16*)(hB + (size_t)N * D);         // E*64 bf16
    u16*   hbf    = g + (size_t)E * 64;                 // N*D bf16
    u16*   W2f    = hbf + (size_t)N * D;                // 65536 bf16
    float* u      = (float*)(W2f + 65536);              // N*D
    float* v      = u + (size_t)N * D;                  // N*D
    float* B      = v + (size_t)N * D;                  // N*D
    u32*   Mt     = (u32*)(B + (size_t)N * D);          // N*1024 u32 (packed bf16 pairs)

    int ndBlocks = (N * D + 255) / 256;
    int eBlocks  = (E + 255) / 256;

    k_hev<<<ndBlocks, 256, 0, stream>>>(x, W_emb, b_emb, W_th, b_th, W_ph, b_ph,
                                        hA, hbf, u, v, a, cnt, cursor, Npad, N);
    k_w2frag<<<256, 256, 0, stream>>>(W2, W2f);
    k_count<<<eBlocks, 256, 0, stream>>>(src, cnt, E);
    k_scan<<<1, 1024, 0, stream>>>(cnt, roff, N);
    k_scatter<<<eBlocks, 256, 0, stream>>>(src, dst, roff, cursor, ssrc, sdst, E);
    k_edge2<<<2048, 256, 0, stream>>>(u, v, ssrc, sdst, W1, b1, g, E);

    int mmBlocks = ((N + 15) / 16) * 8;
    int msgBlocks = (N + 3) / 4;
    float* hc = hA;
    float* hn_ = hB;
    for (int step = 0; step < 3; ++step) {
        k_Mm<<<mmBlocks, 256, 0, stream>>>(hbf, W2f, Mt, N);
        k_B<<<ndBlocks, 256, 0, stream>>>(hc, b2, B, N);
        k_msg2<<<msgBlocks, 256, 0, stream>>>(Mt, B, g, roff, sdst, a, N);
        float* dstbuf = (step == 2) ? (float*)d_out : hn_;
        k_gru<<<(N + 7) / 8, 256, 0, stream>>>(a, hc, W_ih, b_ih, W_hh, b_hh, dstbuf, hbf, N);
        float* t = hc; hc = hn_; hn_ = t;
    }
}

// Round 10
// 294.009 us; speedup vs baseline: 1.1478x; 1.0032x over previous
//
#include <hip/hip_runtime.h>
#include <hip/hip_bf16.h>

#define D 32

typedef const float* fp;
typedef unsigned short u16;
typedef unsigned int u32;

using short8 = __attribute__((ext_vector_type(8))) short;
using f32x4  = __attribute__((ext_vector_type(4))) float;

__device__ __forceinline__ float b2f(u32 lo16) { return __uint_as_float(lo16 << 16); }
__device__ __forceinline__ u16 f2b(float f) {
    u32 x = __float_as_uint(f);
    return (u16)((x + 0x7fffu + ((x >> 16) & 1u)) >> 16);   // RNE
}

// h (f32+bf16), u, v from x; P precomposed in LDS; zeroes a/cnt/cursor
__global__ void k_hev(fp x, fp W_emb, fp b_emb, fp Wth, fp bth, fp Wph, fp bph,
                      float* __restrict__ h, u16* __restrict__ hbf,
                      float* __restrict__ u, float* __restrict__ v,
                      float* __restrict__ a, int* __restrict__ cnt,
                      int* __restrict__ cursor, int Npad, int N) {
    __shared__ float sP[192];
    int tid = threadIdx.x;
    if (tid < 32) {
        int o = tid;
        float au0 = 0.f, au1 = 0.f, cu = 0.f, av0 = 0.f, av1 = 0.f, cv = 0.f;
        for (int i = 0; i < D; ++i) {
            float wt = Wth[i * D + o];
            float wd = Wph[i * D + o] - wt;
            au0 += W_emb[i] * wt;
            au1 += W_emb[D + i] * wt;
            cu  += b_emb[i] * wt;
            av0 += W_emb[i] * wd;
            av1 += W_emb[D + i] * wd;
            cv  += b_emb[i] * wd;
        }
        sP[o]       = au0;
        sP[32 + o]  = au1;
        sP[64 + o]  = cu + bth[o] + bph[o];
        sP[96 + o]  = av0;
        sP[128 + o] = av1;
        sP[160 + o] = cv;
    }
    __syncthreads();
    int t = blockIdx.x * 256 + tid;
    if (t >= N * D) return;
    a[t] = 0.f;
    if (t < Npad) cnt[t] = 0;
    if (t < N) cursor[t] = 0;
    int n = t >> 5, o = t & 31;
    float x0 = x[2 * n], x1 = x[2 * n + 1];
    float hv = x0 * W_emb[o] + x1 * W_emb[D + o] + b_emb[o];
    h[t] = hv;
    hbf[t] = f2b(hv);
    u[t] = x0 * sP[o] + x1 * sP[32 + o] + sP[64 + o];
    v[t] = x0 * sP[96 + o] + x1 * sP[128 + o] + sP[160 + o];
}

// W2 -> MFMA-B-fragment layout
__global__ void k_w2frag(fp W2, u16* __restrict__ W2f) {
    int idx = blockIdx.x * 256 + threadIdx.x;   // 65536 total
    int T = idx >> 9, r = idx & 511, l = r >> 3, j = r & 7;
    int ko = T * 16 + (l & 15);
    int i = (l >> 4) * 8 + j;
    W2f[idx] = f2b(W2[(size_t)(ko >> 5) * 1024 + i * 32 + (ko & 31)]);
}

__global__ void k_count(const int* __restrict__ src, int* __restrict__ cnt, int E) {
    int e = blockIdx.x * 256 + threadIdx.x;
    if (e < E) atomicAdd(&cnt[src[e]], 1);
}

// dual exclusive scan: roff over cnt, toff over ceil(cnt/16)
__global__ void k_scan(const int* __restrict__ cnt, int* __restrict__ roff,
                       int* __restrict__ toff, int N) {
    __shared__ int pe[1024], pt[1024];
    int t = threadIdx.x;
    int per = (N + 1023) / 1024;
    int begin = t * per, end = min(begin + per, N);
    int se = 0, st = 0;
    for (int i = begin; i < end; ++i) { int c = cnt[i]; se += c; st += (c + 15) >> 4; }
    pe[t] = se; pt[t] = st;
    __syncthreads();
    for (int off = 1; off < 1024; off <<= 1) {
        int ve = (t >= off) ? pe[t - off] : 0;
        int vt = (t >= off) ? pt[t - off] : 0;
        __syncthreads();
        pe[t] += ve; pt[t] += vt;
        __syncthreads();
    }
    int pre_e = (t == 0) ? 0 : pe[t - 1];
    int pre_t = (t == 0) ? 0 : pt[t - 1];
    for (int i = begin; i < end; ++i) {
        int c = cnt[i];
        roff[i] = pre_e; pre_e += c;
        toff[i] = pre_t; pre_t += (c + 15) >> 4;
    }
    if (t == 0) { roff[N] = pe[1023]; toff[N] = pt[1023]; }
}

__global__ void k_scatter(const int* __restrict__ src, const int* __restrict__ dst,
                          const int* __restrict__ roff, int* __restrict__ cursor,
                          int* __restrict__ ssrc, int* __restrict__ sdst, int E) {
    int e = blockIdx.x * 256 + threadIdx.x;
    if (e >= E) return;
    int s = src[e];
    int p = roff[s] + atomicAdd(&cursor[s], 1);
    ssrc[p] = s;
    sdst[p] = dst[e];
}

// tile list: one tile per (src, 16-edge group), deterministic order via toff
__global__ void k_tiles(const int* __restrict__ cnt, const int* __restrict__ roff,
                        const int* __restrict__ toff, int* __restrict__ tilS,
                        int* __restrict__ tilB, int N) {
    int s = blockIdx.x * 256 + threadIdx.x;
    if (s >= N) return;
    int deg = cnt[s];
    if (deg == 0) return;
    int base = toff[s], beg = roff[s];
    int nt = (deg + 15) >> 4;
    for (int t = 0; t < nt; ++t) { tilS[base + t] = s; tilB[base + t] = beg + 16 * t; }
}

// cooperative: 8 edges/block; lane o owns g[k=2o,2o+1]; he staged in LDS
__global__ __launch_bounds__(256)
void k_edge2(const float* __restrict__ u, const float* __restrict__ v,
             const int* __restrict__ ssrc, const int* __restrict__ sdst,
             fp W1, fp b1, u16* __restrict__ g, int E) {
    __shared__ float sW1[D * 64];
    __shared__ float sb1[64];
    __shared__ float she[8][D];
    for (int i = threadIdx.x; i < D * 64; i += 256) sW1[i] = W1[i];
    if (threadIdx.x < 64) sb1[threadIdx.x] = b1[threadIdx.x];
    __syncthreads();
    int sub = threadIdx.x >> 5, o = threadIdx.x & 31;
    const float2* w2p = (const float2*)sW1;
    for (int e0 = blockIdx.x * 8; e0 < E; e0 += gridDim.x * 8) {
        int e = e0 + sub;
        if (e < E) {
            int s = ssrc[e], d2 = sdst[e];
            she[sub][o] = fmaxf(u[(size_t)d2 * D + o] + v[(size_t)s * D + o], 0.f);
        }
        __syncthreads();
        if (e < E) {
            float a0 = sb1[2 * o], a1 = sb1[2 * o + 1];
            #pragma unroll
            for (int i = 0; i < D; ++i) {
                float hv = she[sub][i];
                float2 w = w2p[i * 32 + o];
                a0 += hv * w.x;
                a1 += hv * w.y;
            }
            ((u32*)g)[(size_t)e * 32 + o] =
                (u32)f2b(fmaxf(a0, 0.f)) | ((u32)f2b(fmaxf(a1, 0.f)) << 16);
        }
        __syncthreads();
    }
}

// MFMA M-GEMM -> Mt[s][q][o] (u32 = bf16 pair k=2q|2q+1); slice-0 blocks also compute B
__global__ __launch_bounds__(256)
void k_Mm(const u16* __restrict__ hbf, const u16* __restrict__ W2f, const float* __restrict__ h,
          fp b2, u32* __restrict__ Mt, float* __restrict__ B, int N) {
    __shared__ u16 sM[16][264];
    int n0 = (blockIdx.x >> 3) * 16;
    if (n0 >= N) return;
    int koBase = (blockIdx.x & 7) * 256;
    int qb = (blockIdx.x & 7) * 4;
    int w = threadIdx.x >> 6, l = threadIdx.x & 63;
    int arow = n0 + (l & 15);
    if (arow >= N) arow = N - 1;
    short8 afrag = *(const short8*)(hbf + (size_t)arow * 32 + (l >> 4) * 8);
    int T0 = (koBase >> 4) + w * 4;
    const u16* bp = W2f + (size_t)T0 * 512 + l * 8;
    short8 b0 = *(const short8*)(bp);
    short8 b1 = *(const short8*)(bp + 512);
    short8 b2v = *(const short8*)(bp + 1024);
    short8 b3 = *(const short8*)(bp + 1536);
    f32x4 acc0{0.f,0.f,0.f,0.f}, acc1{0.f,0.f,0.f,0.f}, acc2{0.f,0.f,0.f,0.f}, acc3{0.f,0.f,0.f,0.f};
    acc0 = __builtin_amdgcn_mfma_f32_16x16x32_bf16(afrag, b0, acc0, 0, 0, 0);
    acc1 = __builtin_amdgcn_mfma_f32_16x16x32_bf16(afrag, b1, acc1, 0, 0, 0);
    acc2 = __builtin_amdgcn_mfma_f32_16x16x32_bf16(afrag, b2v, acc2, 0, 0, 0);
    acc3 = __builtin_amdgcn_mfma_f32_16x16x32_bf16(afrag, b3, acc3, 0, 0, 0);
    // B (slice 0 only): 16 rows x 32 o, f32 h for accuracy
    if ((blockIdx.x & 7) == 0) {
        int idx = threadIdx.x;
        #pragma unroll
        for (int z = 0; z < 2; ++z, idx += 256) {
            int nn_ = idx >> 5, o = idx & 31;
            if (n0 + nn_ < N) {
                const float* hr = h + (size_t)(n0 + nn_) * 32;
                float acc = 0.f;
                #pragma unroll 8
                for (int i = 0; i < 32; ++i) acc += hr[i] * b2[i * 32 + o];
                B[(size_t)(n0 + nn_) * 32 + o] = acc;
            }
        }
    }
    int rbase = (l >> 4) * 4, col = l & 15;
    #pragma unroll
    for (int r = 0; r < 4; ++r) {
        sM[rbase + r][w * 64 +  0 + col] = f2b(acc0[r]);
        sM[rbase + r][w * 64 + 16 + col] = f2b(acc1[r]);
        sM[rbase + r][w * 64 + 32 + col] = f2b(acc2[r]);
        sM[rbase + r][w * 64 + 48 + col] = f2b(acc3[r]);
    }
    __syncthreads();
    int i = threadIdx.x >> 4;
    int base = (threadIdx.x & 15) * 8;
    if (n0 + i >= N) return;
    u32 out[8];
    #pragma unroll
    for (int z = 0; z < 8; ++z) {
        int idx = base + z;
        int qq = idx >> 5;
        int o  = idx & 31;
        u32 lo = sM[i][(2 * qq) * 32 + o];
        u32 hi = sM[i][(2 * qq + 1) * 32 + o];
        out[z] = lo | (hi << 16);
    }
    u32* dstp = Mt + (size_t)(n0 + i) * 1024 + qb * 32 + base;
    *(uint4*)dstp       = make_uint4(out[0], out[1], out[2], out[3]);
    *(uint4*)(dstp + 4) = make_uint4(out[4], out[5], out[6], out[7]);
}

// MFMA message kernel: one wave per (src, <=16-edge) tile; no LDS.
// A = g rows (16 edges x 64 k), B = Mt[s] (64 k x 32 o, two 16-o tiles), C += atomically.
__global__ __launch_bounds__(256)
void k_msg3(const u32* __restrict__ Mt, const float* __restrict__ B,
            const u32* __restrict__ g32, const int* __restrict__ tilS,
            const int* __restrict__ tilB, const int* __restrict__ roff,
            const int* __restrict__ toffN, const int* __restrict__ sdst,
            float* __restrict__ a) {
    int T_total = *toffN;
    int tile = blockIdx.x * 4 + (threadIdx.x >> 6);
    if (tile >= T_total) return;
    int l = threadIdx.x & 63;
    int s = tilS[tile], beg = tilB[tile], end = roff[s + 1];
    // A-frags (k-half 0 and 1) from g; zero for invalid edges
    union { uint4 u; short8 v; } A0, A1;
    A0.u = make_uint4(0, 0, 0, 0);
    A1.u = make_uint4(0, 0, 0, 0);
    int arow = beg + (l & 15);
    if (arow < end) {
        const uint4* gp = (const uint4*)(g32 + (size_t)arow * 32);
        A0.u = gp[l >> 4];
        A1.u = gp[4 + (l >> 4)];
    }
    // B-frags: o-tile 0/1 x k-half 0/1
    const u32* mrow = Mt + (size_t)s * 1024;
    int oc = l & 15, qb = (l >> 4) * 4;
    union { u32 w[4]; short8 v; } B00, B10, B01, B11;
    #pragma unroll
    for (int jj = 0; jj < 4; ++jj) {
        B00.w[jj] = mrow[(qb + jj) * 32 + oc];
        B10.w[jj] = mrow[(16 + qb + jj) * 32 + oc];
        B01.w[jj] = mrow[(qb + jj) * 32 + 16 + oc];
        B11.w[jj] = mrow[(16 + qb + jj) * 32 + 16 + oc];
    }
    f32x4 c0{0.f,0.f,0.f,0.f}, c1{0.f,0.f,0.f,0.f};
    c0 = __builtin_amdgcn_mfma_f32_16x16x32_bf16(A0.v, B00.v, c0, 0, 0, 0);
    c0 = __builtin_amdgcn_mfma_f32_16x16x32_bf16(A1.v, B10.v, c0, 0, 0, 0);
    c1 = __builtin_amdgcn_mfma_f32_16x16x32_bf16(A0.v, B01.v, c1, 0, 0, 0);
    c1 = __builtin_amdgcn_mfma_f32_16x16x32_bf16(A1.v, B11.v, c1, 0, 0, 0);
    float Bs0 = B[(size_t)s * 32 + oc];
    float Bs1 = B[(size_t)s * 32 + 16 + oc];
    int rb = (l >> 4) * 4;
    #pragma unroll
    for (int r = 0; r < 4; ++r) {
        int e = beg + rb + r;
        if (e < end) {
            int d = sdst[e];
            atomicAdd(&a[(size_t)d * 32 + oc],      c0[r] + Bs0);
            atomicAdd(&a[(size_t)d * 32 + 16 + oc], c1[r] + Bs1);
        }
    }
}

// torch GRUCell, 32 nodes/block, weights in LDS; zeroes a in place; writes f32 + bf16 h
__global__ __launch_bounds__(256)
void k_gru(float* __restrict__ a, const float* __restrict__ h,
           fp W_ih, fp b_ih, fp W_hh, fp b_hh,
           float* __restrict__ hout, u16* __restrict__ hbf, int N) {
    __shared__ float sWi[D * 96], sWh[D * 96], sbi[96], sbh[96];
    __shared__ float sa[32][D], sh[32][D];
    for (int i = threadIdx.x; i < D * 96; i += 256) { sWi[i] = W_ih[i]; sWh[i] = W_hh[i]; }
    if (threadIdx.x < 96) { sbi[threadIdx.x] = b_ih[threadIdx.x]; sbh[threadIdx.x] = b_hh[threadIdx.x]; }
    int n0 = blockIdx.x * 32;
    for (int i = threadIdx.x; i < 32 * D; i += 256) {
        int n = n0 + (i >> 5);
        if (n < N) {
            size_t idx = (size_t)n * D + (i & 31);
            sa[i >> 5][i & 31] = a[idx];
            sh[i >> 5][i & 31] = h[idx];
            a[idx] = 0.f;
        }
    }
    __syncthreads();
    int o = threadIdx.x & 31;
    #pragma unroll
    for (int z = 0; z < 4; ++z) {
        int sub = (threadIdx.x >> 5) + z * 8;
        int n = n0 + sub;
        if (n >= N) continue;
        float ir = sbi[o], iz = sbi[D + o], in_ = sbi[2 * D + o];
        float hr = sbh[o], hz = sbh[D + o], hn = sbh[2 * D + o];
        #pragma unroll
        for (int i = 0; i < D; ++i) {
            float av = sa[sub][i], hv = sh[sub][i];
            ir += av * sWi[i * 96 + o];
            iz += av * sWi[i * 96 + D + o];
            in_ += av * sWi[i * 96 + 2 * D + o];
            hr += hv * sWh[i * 96 + o];
            hz += hv * sWh[i * 96 + D + o];
            hn += hv * sWh[i * 96 + 2 * D + o];
        }
        float r = 1.f / (1.f + __expf(-(ir + hr)));
        float zz = 1.f / (1.f + __expf(-(iz + hz)));
        float nn = tanhf(in_ + r * hn);
        float hv2 = (1.f - zz) * nn + zz * sh[sub][o];
        size_t idx = (size_t)n * D + o;
        hout[idx] = hv2;
        hbf[idx] = f2b(hv2);
    }
}

extern "C" void kernel_launch(void* const* d_in, const int* in_sizes, int n_in,
                              void* d_out, int out_size, void* d_ws, size_t ws_size,
                              hipStream_t stream) {
    fp x      = (fp)d_in[0];
    const int* src = (const int*)d_in[1];
    const int* dst = (const int*)d_in[2];
    fp W_emb  = (fp)d_in[3];
    fp b_emb  = (fp)d_in[4];
    fp W_th   = (fp)d_in[5];
    fp b_th   = (fp)d_in[6];
    fp W_ph   = (fp)d_in[7];
    fp b_ph   = (fp)d_in[8];
    fp W1     = (fp)d_in[9];
    fp b1     = (fp)d_in[10];
    fp W2     = (fp)d_in[11];
    fp b2     = (fp)d_in[12];
    fp W_ih   = (fp)d_in[13];
    fp b_ih   = (fp)d_in[14];
    fp W_hh   = (fp)d_in[15];
    fp b_hh   = (fp)d_in[16];

    const int N = in_sizes[0] / 2;
    const int E = in_sizes[1];
    const int Npad = N + 4 - (N % 4);
    const int maxTiles = N + (E + 15) / 16;

    float* a      = (float*)d_ws;                       // N*D f32
    int*   cnt    = (int*)(a + (size_t)N * D);          // Npad
    int*   cursor = cnt + Npad;                         // N
    int*   roff   = cursor + N;                         // Npad (N+1 used)
    int*   toff   = roff + Npad;                        // Npad (N+1 used)
    int*   ssrc   = toff + Npad;                        // E
    int*   sdst   = ssrc + E;                           // E
    int*   tilS   = sdst + E;                           // maxTiles
    int*   tilB   = tilS + maxTiles;                    // maxTiles
    float* hA     = (float*)(tilB + maxTiles);          // N*D
    float* hB     = hA + (size_t)N * D;                 // N*D
    u16*   g      = (u16*)(hB + (size_t)N * D);         // E*64 bf16
    u16*   hbf    = g + (size_t)E * 64;                 // N*D bf16
    u16*   W2f    = hbf + (size_t)N * D;                // 65536 bf16
    float* u      = (float*)(W2f + 65536);              // N*D
    float* v      = u + (size_t)N * D;                  // N*D
    float* B      = v + (size_t)N * D;                  // N*D
    u32*   Mt     = (u32*)(B + (size_t)N * D);          // N*1024 u32

    int ndBlocks = (N * D + 255) / 256;
    int eBlocks  = (E + 255) / 256;
    int nBlocks  = (N + 255) / 256;

    k_hev<<<ndBlocks, 256, 0, stream>>>(x, W_emb, b_emb, W_th, b_th, W_ph, b_ph,
                                        hA, hbf, u, v, a, cnt, cursor, Npad, N);
    k_w2frag<<<256, 256, 0, stream>>>(W2, W2f);
    k_count<<<eBlocks, 256, 0, stream>>>(src, cnt, E);
    k_scan<<<1, 1024, 0, stream>>>(cnt, roff, toff, N);
    k_scatter<<<eBlocks, 256, 0, stream>>>(src, dst, roff, cursor, ssrc, sdst, E);
    k_tiles<<<nBlocks, 256, 0, stream>>>(cnt, roff, toff, tilS, tilB, N);
    k_edge2<<<2048, 256, 0, stream>>>(u, v, ssrc, sdst, W1, b1, g, E);

    int mmBlocks  = ((N + 15) / 16) * 8;
    int msgBlocks = (maxTiles + 3) / 4;
    float* hc = hA;
    float* hn_ = hB;
    for (int step = 0; step < 3; ++step) {
        k_Mm<<<mmBlocks, 256, 0, stream>>>(hbf, W2f, hc, b2, Mt, B, N);
        k_msg3<<<msgBlocks, 256, 0, stream>>>(Mt, B, (const u32*)g, tilS, tilB,
                                              roff, toff + N, sdst, a);
        float* dstbuf = (step == 2) ? (float*)d_out : hn_;
        k_gru<<<(N + 31) / 32, 256, 0, stream>>>(a, hc, W_ih, b_ih, W_hh, b_hh, dstbuf, hbf, N);
        float* t = hc; hc = hn_; hn_ = t;
    }
}